// Round 6
// baseline (830.379 us; speedup 1.0000x reference)
//
#include <hip/hip_runtime.h>
#include <hip/hip_bf16.h>

#define IN_DIM 128
#define HID    64
#define OUTD   64
#define NPART  8

typedef __attribute__((ext_vector_type(8))) short bf16x8;
typedef __attribute__((ext_vector_type(4))) float f32x4;

__device__ __forceinline__ float gelu_exact(float v) {
    return v * 0.5f * (1.0f + erff(v * 0.70710678118654752f));
}
__device__ __forceinline__ short f2bf(float f) {
    __hip_bfloat16 b = __float2bfloat16(f);   // RNE
    return *reinterpret_cast<short*>(&b);
}
__device__ __forceinline__ float bf2f(ushort u) {
    return __uint_as_float(((unsigned)u) << 16);
}

#define WREDUCE(v) { v += __shfl_xor(v,32,64); v += __shfl_xor(v,16,64); \
                     v += __shfl_xor(v,8,64);  v += __shfl_xor(v,4,64);  \
                     v += __shfl_xor(v,2,64);  v += __shfl_xor(v,1,64); }

// ---------------------------------------------------------------------------
// K1: node projection via MFMA bf16 (unchanged; not the bottleneck).
// ---------------------------------------------------------------------------
__global__ __launch_bounds__(256) void gat_node_proj_mfma(
    const float* __restrict__ x, const float* __restrict__ w_in,
    const float* __restrict__ b_in, const float* __restrict__ w,
    const float* __restrict__ a,
    ushort* __restrict__ zb, float* __restrict__ s1, float* __restrict__ s2,
    int n_nodes, int ntiles)
{
    __shared__ ushort h0s[4][16 * 64];

    const int tid = threadIdx.x;
    const int wv = tid >> 6, l = tid & 63;
    const int c = l & 15, g = l >> 4;

    bf16x8 B1[4][4];
    #pragma unroll
    for (int s = 0; s < 4; ++s)
        #pragma unroll
        for (int t = 0; t < 4; ++t) {
            bf16x8 f;
            #pragma unroll
            for (int e = 0; e < 8; ++e)
                f[e] = f2bf(w_in[(s * 32 + g * 8 + e) * HID + t * 16 + c]);
            B1[s][t] = f;
        }
    bf16x8 B2[2][4];
    #pragma unroll
    for (int s = 0; s < 2; ++s)
        #pragma unroll
        for (int t = 0; t < 4; ++t) {
            bf16x8 f;
            #pragma unroll
            for (int e = 0; e < 8; ++e)
                f[e] = f2bf(w[(s * 32 + g * 8 + e) * OUTD + t * 16 + c]);
            B2[s][t] = f;
        }
    float bias[4], a1c[4], a2c[4];
    #pragma unroll
    for (int t = 0; t < 4; ++t) {
        bias[t] = b_in[t * 16 + c];
        a1c[t]  = a[t * 16 + c];
        a2c[t]  = a[OUTD + t * 16 + c];
    }

    ushort* hrow = &h0s[wv][0];

    for (int tile = blockIdx.x; tile < ntiles; tile += gridDim.x) {
        const int nbase = tile * 64 + wv * 16;

        const int row = min(nbase + c, n_nodes - 1);
        const float* xp = x + (size_t)row * IN_DIM;
        bf16x8 A1[4];
        #pragma unroll
        for (int s = 0; s < 4; ++s) {
            const float4 u0 = *(const float4*)(xp + s * 32 + g * 8);
            const float4 u1 = *(const float4*)(xp + s * 32 + g * 8 + 4);
            bf16x8 f;
            f[0] = f2bf(u0.x); f[1] = f2bf(u0.y); f[2] = f2bf(u0.z); f[3] = f2bf(u0.w);
            f[4] = f2bf(u1.x); f[5] = f2bf(u1.y); f[6] = f2bf(u1.z); f[7] = f2bf(u1.w);
            A1[s] = f;
        }

        #pragma unroll
        for (int t = 0; t < 4; ++t) {
            f32x4 acc = {0.f, 0.f, 0.f, 0.f};
            #pragma unroll
            for (int s = 0; s < 4; ++s)
                acc = __builtin_amdgcn_mfma_f32_16x16x32_bf16(A1[s], B1[s][t], acc, 0, 0, 0);
            #pragma unroll
            for (int r = 0; r < 4; ++r) {
                const int m = g * 4 + r;
                const int n = t * 16 + c;
                const float h0 = gelu_exact(acc[r] + bias[t]);
                hrow[m * 64 + (n ^ ((m & 7) << 3))] = (ushort)f2bf(h0);
            }
        }
        __syncthreads();

        bf16x8 A2[2];
        #pragma unroll
        for (int s = 0; s < 2; ++s) {
            const int k = s * 32 + g * 8;
            A2[s] = *(const bf16x8*)(hrow + c * 64 + (k ^ ((c & 7) << 3)));
        }

        f32x4 C2[4];
        #pragma unroll
        for (int t = 0; t < 4; ++t) {
            f32x4 acc = {0.f, 0.f, 0.f, 0.f};
            acc = __builtin_amdgcn_mfma_f32_16x16x32_bf16(A2[0], B2[0][t], acc, 0, 0, 0);
            acc = __builtin_amdgcn_mfma_f32_16x16x32_bf16(A2[1], B2[1][t], acc, 0, 0, 0);
            C2[t] = acc;
        }

        float p1v[4] = {0.f, 0.f, 0.f, 0.f}, p2v[4] = {0.f, 0.f, 0.f, 0.f};
        #pragma unroll
        for (int t = 0; t < 4; ++t)
            #pragma unroll
            for (int r = 0; r < 4; ++r) {
                p1v[r] = fmaf(C2[t][r], a1c[t], p1v[r]);
                p2v[r] = fmaf(C2[t][r], a2c[t], p2v[r]);
                const int node = nbase + g * 4 + r;
                if (node < n_nodes)
                    zb[(size_t)node * OUTD + t * 16 + c] = (ushort)f2bf(C2[t][r]);
            }

        #pragma unroll
        for (int r = 0; r < 4; ++r) {
            p1v[r] += __shfl_xor(p1v[r], 1, 64);
            p1v[r] += __shfl_xor(p1v[r], 2, 64);
            p1v[r] += __shfl_xor(p1v[r], 4, 64);
            p1v[r] += __shfl_xor(p1v[r], 8, 64);
            p2v[r] += __shfl_xor(p2v[r], 1, 64);
            p2v[r] += __shfl_xor(p2v[r], 2, 64);
            p2v[r] += __shfl_xor(p2v[r], 4, 64);
            p2v[r] += __shfl_xor(p2v[r], 8, 64);
        }
        const float v1 = (c == 0) ? p1v[0] : (c == 1) ? p1v[1] : (c == 2) ? p1v[2] : p1v[3];
        const float v2 = (c == 0) ? p2v[0] : (c == 1) ? p2v[1] : (c == 2) ? p2v[2] : p2v[3];
        const int snode = nbase + g * 4 + c;
        if (c < 4 && snode < n_nodes) { s1[snode] = v1; s2[snode] = v2; }
        __syncthreads();
    }
}

// ---------------------------------------------------------------------------
// CSR build v3: single-read 8-way bucket partition, WAVE-BALLOT aggregated
// (R5's per-element LDS atomics serialized: 340us, 441K bank-conflicts).
// Per wave: 256 edges via dwordx4, 8 ballot-masks per partition, ONE global
// atomic per partition per wave-iter, lanes write their claimed contiguous
// slots via prefix-popc. No LDS anywhere in the hot path.
// Pack: (dst_local<<17)|src needs n_nodes<=131072, part_sz<=16384.
// ---------------------------------------------------------------------------
__global__ __launch_bounds__(256) void k_count8(
    const int* __restrict__ dst, int* __restrict__ cnt8, int n_edges, int part_sz)
{
    __shared__ int csh[4][NPART];
    const int wv = threadIdx.x >> 6, lane = threadIdx.x & 63;
    int local = 0;

    const int tiles = (n_edges + 1023) >> 10;   // 1024 edges per block-iter (4/lane/wave... 256 threads*4)
    for (int t = blockIdx.x; t < tiles; t += gridDim.x) {
        const int base = (t << 10) + (threadIdx.x << 2);
        int p0 = -1, p1 = -1, p2 = -1, p3 = -1;
        if (base + 3 < n_edges) {
            const int4 d4 = *(const int4*)(dst + base);
            p0 = d4.x / part_sz; p1 = d4.y / part_sz;
            p2 = d4.z / part_sz; p3 = d4.w / part_sz;
        } else {
            if (base + 0 < n_edges) p0 = dst[base + 0] / part_sz;
            if (base + 1 < n_edges) p1 = dst[base + 1] / part_sz;
            if (base + 2 < n_edges) p2 = dst[base + 2] / part_sz;
            if (base + 3 < n_edges) p3 = dst[base + 3] / part_sz;
        }
        #pragma unroll
        for (int pp = 0; pp < NPART; ++pp) {
            const int k = __popcll(__ballot(p0 == pp)) + __popcll(__ballot(p1 == pp))
                        + __popcll(__ballot(p2 == pp)) + __popcll(__ballot(p3 == pp));
            if (lane == pp) local += k;
        }
    }
    if (lane < NPART) csh[wv][lane] = local;
    __syncthreads();
    if (wv == 0 && lane < NPART) {
        const int s = csh[0][lane] + csh[1][lane] + csh[2][lane] + csh[3][lane];
        if (s > 0) atomicAdd(&cnt8[lane], s);
    }
}

__global__ void k_off8(const int* __restrict__ cnt8, int* __restrict__ off8)
{
    if (threadIdx.x == 0) {
        int a = 0;
        for (int p = 0; p < NPART; ++p) { off8[p] = a; a += cnt8[p]; }
        off8[NPART] = a;
    }
}

__global__ __launch_bounds__(256) void k_bucket(
    const int* __restrict__ src, const int* __restrict__ dst,
    const int* __restrict__ off8, int* __restrict__ tail8,
    unsigned* __restrict__ bkt, int n_edges, int part_sz)
{
    const int lane = threadIdx.x & 63;
    const int gw = (blockIdx.x * 256 + threadIdx.x) >> 6;
    const int nw = (gridDim.x * 256) >> 6;
    const unsigned long long below = (lane == 63) ? 0x7FFFFFFFFFFFFFFFull
                                                  : ((1ull << lane) - 1ull);

    const int tiles = (n_edges + 255) >> 8;     // 256 edges per wave-iter
    for (int t = gw; t < tiles; t += nw) {
        const int base = (t << 8) + (lane << 2);   // 4 consecutive edges/lane
        int p[4]; unsigned pk[4];
        if (base + 3 < n_edges) {
            const int4 d4 = *(const int4*)(dst + base);
            const int4 s4 = *(const int4*)(src + base);
            p[0] = d4.x / part_sz; pk[0] = ((unsigned)(d4.x - p[0] * part_sz) << 17) | (unsigned)s4.x;
            p[1] = d4.y / part_sz; pk[1] = ((unsigned)(d4.y - p[1] * part_sz) << 17) | (unsigned)s4.y;
            p[2] = d4.z / part_sz; pk[2] = ((unsigned)(d4.z - p[2] * part_sz) << 17) | (unsigned)s4.z;
            p[3] = d4.w / part_sz; pk[3] = ((unsigned)(d4.w - p[3] * part_sz) << 17) | (unsigned)s4.w;
        } else {
            #pragma unroll
            for (int j = 0; j < 4; ++j) {
                if (base + j < n_edges) {
                    const int d = dst[base + j];
                    p[j] = d / part_sz;
                    pk[j] = ((unsigned)(d - p[j] * part_sz) << 17) | (unsigned)src[base + j];
                } else p[j] = -1;
            }
        }
        #pragma unroll
        for (int pp = 0; pp < NPART; ++pp) {
            const unsigned long long m0 = __ballot(p[0] == pp);
            const unsigned long long m1 = __ballot(p[1] == pp);
            const unsigned long long m2 = __ballot(p[2] == pp);
            const unsigned long long m3 = __ballot(p[3] == pp);
            const int k0 = __popcll(m0), k1 = __popcll(m1);
            const int k2 = __popcll(m2), k3 = __popcll(m3);
            const int kt = k0 + k1 + k2 + k3;
            if (kt == 0) continue;
            int b0 = 0;
            if (lane == 0) b0 = atomicAdd(&tail8[pp], kt);
            b0 = __shfl(b0, 0, 64);
            const int go = off8[pp] + b0;
            if ((m0 >> lane) & 1) bkt[go + __popcll(m0 & below)] = pk[0];
            if ((m1 >> lane) & 1) bkt[go + k0 + __popcll(m1 & below)] = pk[1];
            if ((m2 >> lane) & 1) bkt[go + k0 + k1 + __popcll(m2 & below)] = pk[2];
            if ((m3 >> lane) & 1) bkt[go + k0 + k1 + k2 + __popcll(m3 & below)] = pk[3];
        }
    }
}

__global__ __launch_bounds__(256) void k_hist_b(
    const unsigned* __restrict__ bkt, const int* __restrict__ cnt8,
    const int* __restrict__ off8, int* __restrict__ deg, int part_sz)
{
    const int p = blockIdx.x & (NPART - 1);
    const int n = cnt8[p];
    const unsigned* b = bkt + off8[p];
    const int lo = p * part_sz;
    const int stride = (gridDim.x >> 3) * 256;
    for (int i = (blockIdx.x >> 3) * 256 + threadIdx.x; i < n; i += stride)
        atomicAdd(&deg[lo + (int)(b[i] >> 17)], 1);
}

__global__ __launch_bounds__(256) void k_scatter_b(
    const unsigned* __restrict__ bkt, const int* __restrict__ cnt8,
    const int* __restrict__ off8, int* __restrict__ cursor,
    int* __restrict__ csr, int part_sz)
{
    const int p = blockIdx.x & (NPART - 1);
    const int n = cnt8[p];
    const unsigned* b = bkt + off8[p];
    const int lo = p * part_sz;
    const int stride = (gridDim.x >> 3) * 256;
    for (int i = (blockIdx.x >> 3) * 256 + threadIdx.x; i < n; i += stride) {
        const unsigned v = b[i];
        const int d = lo + (int)(v >> 17);
        const int pos = atomicAdd(&cursor[d], 1);
        csr[pos] = (int)(v & 0x1FFFFu);
    }
}

__global__ __launch_bounds__(1024) void k_scan_block(
    const int* __restrict__ deg, int* __restrict__ rs,
    int* __restrict__ bsum, int n)
{
    __shared__ int buf[1024];
    const int tid = threadIdx.x;
    const int gid = blockIdx.x * 1024 + tid;
    const int v = (gid < n) ? deg[gid] : 0;
    buf[tid] = v;
    __syncthreads();
    #pragma unroll
    for (int off = 1; off < 1024; off <<= 1) {
        int t = (tid >= off) ? buf[tid - off] : 0;
        __syncthreads();
        buf[tid] += t;
        __syncthreads();
    }
    if (gid < n) rs[gid] = buf[tid] - v;
    if (tid == 1023) bsum[blockIdx.x] = buf[1023];
}

__global__ __launch_bounds__(128) void k_scan_bsum(int* __restrict__ bsum, int nb)
{
    __shared__ int buf[128];
    const int tid = threadIdx.x;
    const int v = (tid < nb) ? bsum[tid] : 0;
    buf[tid] = v;
    __syncthreads();
    #pragma unroll
    for (int off = 1; off < 128; off <<= 1) {
        int t = (tid >= off) ? buf[tid - off] : 0;
        __syncthreads();
        buf[tid] += t;
        __syncthreads();
    }
    if (tid < nb) bsum[tid] = buf[tid] - v;
}

__global__ __launch_bounds__(1024) void k_add_off(
    int* __restrict__ rs, int* __restrict__ cursor,
    const int* __restrict__ bsum, int n)
{
    const int gid = blockIdx.x * 1024 + threadIdx.x;
    if (gid < n) {
        const int v = rs[gid] + bsum[blockIdx.x];
        rs[gid] = v;
        cursor[gid] = v;
    }
}

// ---------------------------------------------------------------------------
// K_agg: wave per dst node, unroll-4 over edges (4 gathers in flight).
// ---------------------------------------------------------------------------
__global__ __launch_bounds__(256) void gat_agg(
    const int* __restrict__ rs, const int* __restrict__ deg,
    const int* __restrict__ csr,
    const float* __restrict__ s1, const float* __restrict__ s2,
    const ushort* __restrict__ zb, float* __restrict__ h, int n_nodes)
{
    const int wv = threadIdx.x >> 6, lane = threadIdx.x & 63;
    const int node = blockIdx.x * 4 + wv;
    if (node >= n_nodes) return;

    const int base = rs[node];
    const int cnt = deg[node];
    const float s2d = s2[node];

    float acc = 0.f, den = 0.f;
    for (int c0 = 0; c0 < cnt; c0 += 64) {
        const int m = min(64, cnt - c0);
        int sidx = 0;
        float exv = 0.f;
        if (lane < m) {
            sidx = csr[base + c0 + lane];
            float e = s1[sidx] + s2d;
            e = e > 0.f ? e : 0.01f * e;
            exv = __expf(e);
        }
        float dsum = exv;
        WREDUCE(dsum);
        den += dsum;

        const int mr = (m + 3) & ~3;
        for (int j = 0; j < mr; j += 4) {
            const int   i0 = __shfl(sidx, j,     64);
            const int   i1 = __shfl(sidx, j + 1, 64);
            const int   i2 = __shfl(sidx, j + 2, 64);
            const int   i3 = __shfl(sidx, j + 3, 64);
            const float e0 = __shfl(exv,  j,     64);
            const float e1 = __shfl(exv,  j + 1, 64);
            const float e2 = __shfl(exv,  j + 2, 64);
            const float e3 = __shfl(exv,  j + 3, 64);
            const float v0 = bf2f(zb[(size_t)i0 * OUTD + lane]);
            const float v1 = bf2f(zb[(size_t)i1 * OUTD + lane]);
            const float v2 = bf2f(zb[(size_t)i2 * OUTD + lane]);
            const float v3 = bf2f(zb[(size_t)i3 * OUTD + lane]);
            acc = fmaf(e0, v0, acc);
            acc = fmaf(e1, v1, acc);
            acc = fmaf(e2, v2, acc);
            acc = fmaf(e3, v3, acc);
        }
    }
    h[(size_t)node * OUTD + lane] = acc / fmaxf(den, 1e-9f);
}

extern "C" void kernel_launch(void* const* d_in, const int* in_sizes, int n_in,
                              void* d_out, int out_size, void* d_ws, size_t ws_size,
                              hipStream_t stream)
{
    const float* x    = (const float*)d_in[0];
    const float* w_in = (const float*)d_in[1];
    const float* b_in = (const float*)d_in[2];
    const float* w    = (const float*)d_in[3];
    const float* a    = (const float*)d_in[4];
    const int*   src  = (const int*)d_in[5];
    const int*   dst  = (const int*)d_in[6];
    const int n_nodes = in_sizes[0] / IN_DIM;
    const int n_edges = in_sizes[5];

    float* h = (float*)d_out;

    // workspace layout (~28 MB)
    ushort*   zb     = (ushort*)d_ws;                        // n_nodes*64 bf16
    float*    s1     = (float*)(zb + (size_t)n_nodes * OUTD);
    float*    s2     = s1 + n_nodes;
    int*      deg    = (int*)(s2 + n_nodes);                 // n_nodes
    int*      cnt8   = deg + n_nodes;                        // 8
    int*      tail8  = cnt8 + NPART;                         // 8
    int*      off8   = tail8 + NPART;                        // 9 (+pad to 64)
    int*      rs     = deg + n_nodes + 64;                   // n_nodes
    int*      cursor = rs + n_nodes;                         // n_nodes
    int*      bsum   = cursor + n_nodes;                     // 128
    int*      csr    = bsum + 128;                           // n_edges
    unsigned* bkt    = (unsigned*)(csr + n_edges);           // n_edges

    const int nb = (n_nodes + 1023) / 1024;
    const int ntiles = (n_nodes + 63) / 64;
    const int part_sz = (n_nodes + NPART - 1) / NPART;

    // zero deg + cnt8 + tail8 (+pad) in one memset
    hipMemsetAsync(deg, 0, (size_t)(n_nodes + 64) * sizeof(int), stream);

    k_count8<<<1600, 256, 0, stream>>>(dst, cnt8, n_edges, part_sz);
    k_off8<<<1, 64, 0, stream>>>(cnt8, off8);
    k_bucket<<<1600, 256, 0, stream>>>(src, dst, off8, tail8, bkt, n_edges, part_sz);
    k_hist_b<<<2048, 256, 0, stream>>>(bkt, cnt8, off8, deg, part_sz);
    k_scan_block<<<nb, 1024, 0, stream>>>(deg, rs, bsum, n_nodes);
    k_scan_bsum<<<1, 128, 0, stream>>>(bsum, nb);
    k_add_off<<<nb, 1024, 0, stream>>>(rs, cursor, bsum, n_nodes);
    k_scatter_b<<<2048, 256, 0, stream>>>(bkt, cnt8, off8, cursor, csr, part_sz);

    gat_node_proj_mfma<<<523, 256, 0, stream>>>(x, w_in, b_in, w, a,
                                                zb, s1, s2, n_nodes, ntiles);

    gat_agg<<<(n_nodes + 3) / 4, 256, 0, stream>>>(rs, deg, csr, s1, s2, zb, h, n_nodes);
}

// Round 7
// 280.160 us; speedup vs baseline: 2.9639x; 2.9639x over previous
//
#include <hip/hip_runtime.h>
#include <hip/hip_bf16.h>

#define IN_DIM 128
#define HID    64
#define OUTD   64
#define NPART  8
#define BKT_BLOCKS 1600   // k_bcount / k_bwrite grid; NW = BKT_BLOCKS*4 waves

typedef __attribute__((ext_vector_type(8))) short bf16x8;
typedef __attribute__((ext_vector_type(4))) float f32x4;

__device__ __forceinline__ float gelu_exact(float v) {
    return v * 0.5f * (1.0f + erff(v * 0.70710678118654752f));
}
__device__ __forceinline__ short f2bf(float f) {
    __hip_bfloat16 b = __float2bfloat16(f);   // RNE
    return *reinterpret_cast<short*>(&b);
}
__device__ __forceinline__ float bf2f(ushort u) {
    return __uint_as_float(((unsigned)u) << 16);
}

#define WREDUCE(v) { v += __shfl_xor(v,32,64); v += __shfl_xor(v,16,64); \
                     v += __shfl_xor(v,8,64);  v += __shfl_xor(v,4,64);  \
                     v += __shfl_xor(v,2,64);  v += __shfl_xor(v,1,64); }

// ---------------------------------------------------------------------------
// K1: node projection via MFMA bf16 (unchanged; not the bottleneck).
// ---------------------------------------------------------------------------
__global__ __launch_bounds__(256) void gat_node_proj_mfma(
    const float* __restrict__ x, const float* __restrict__ w_in,
    const float* __restrict__ b_in, const float* __restrict__ w,
    const float* __restrict__ a,
    ushort* __restrict__ zb, float* __restrict__ s1, float* __restrict__ s2,
    int n_nodes, int ntiles)
{
    __shared__ ushort h0s[4][16 * 64];

    const int tid = threadIdx.x;
    const int wv = tid >> 6, l = tid & 63;
    const int c = l & 15, g = l >> 4;

    bf16x8 B1[4][4];
    #pragma unroll
    for (int s = 0; s < 4; ++s)
        #pragma unroll
        for (int t = 0; t < 4; ++t) {
            bf16x8 f;
            #pragma unroll
            for (int e = 0; e < 8; ++e)
                f[e] = f2bf(w_in[(s * 32 + g * 8 + e) * HID + t * 16 + c]);
            B1[s][t] = f;
        }
    bf16x8 B2[2][4];
    #pragma unroll
    for (int s = 0; s < 2; ++s)
        #pragma unroll
        for (int t = 0; t < 4; ++t) {
            bf16x8 f;
            #pragma unroll
            for (int e = 0; e < 8; ++e)
                f[e] = f2bf(w[(s * 32 + g * 8 + e) * OUTD + t * 16 + c]);
            B2[s][t] = f;
        }
    float bias[4], a1c[4], a2c[4];
    #pragma unroll
    for (int t = 0; t < 4; ++t) {
        bias[t] = b_in[t * 16 + c];
        a1c[t]  = a[t * 16 + c];
        a2c[t]  = a[OUTD + t * 16 + c];
    }

    ushort* hrow = &h0s[wv][0];

    for (int tile = blockIdx.x; tile < ntiles; tile += gridDim.x) {
        const int nbase = tile * 64 + wv * 16;

        const int row = min(nbase + c, n_nodes - 1);
        const float* xp = x + (size_t)row * IN_DIM;
        bf16x8 A1[4];
        #pragma unroll
        for (int s = 0; s < 4; ++s) {
            const float4 u0 = *(const float4*)(xp + s * 32 + g * 8);
            const float4 u1 = *(const float4*)(xp + s * 32 + g * 8 + 4);
            bf16x8 f;
            f[0] = f2bf(u0.x); f[1] = f2bf(u0.y); f[2] = f2bf(u0.z); f[3] = f2bf(u0.w);
            f[4] = f2bf(u1.x); f[5] = f2bf(u1.y); f[6] = f2bf(u1.z); f[7] = f2bf(u1.w);
            A1[s] = f;
        }

        #pragma unroll
        for (int t = 0; t < 4; ++t) {
            f32x4 acc = {0.f, 0.f, 0.f, 0.f};
            #pragma unroll
            for (int s = 0; s < 4; ++s)
                acc = __builtin_amdgcn_mfma_f32_16x16x32_bf16(A1[s], B1[s][t], acc, 0, 0, 0);
            #pragma unroll
            for (int r = 0; r < 4; ++r) {
                const int m = g * 4 + r;
                const int n = t * 16 + c;
                const float h0 = gelu_exact(acc[r] + bias[t]);
                hrow[m * 64 + (n ^ ((m & 7) << 3))] = (ushort)f2bf(h0);
            }
        }
        __syncthreads();

        bf16x8 A2[2];
        #pragma unroll
        for (int s = 0; s < 2; ++s) {
            const int k = s * 32 + g * 8;
            A2[s] = *(const bf16x8*)(hrow + c * 64 + (k ^ ((c & 7) << 3)));
        }

        f32x4 C2[4];
        #pragma unroll
        for (int t = 0; t < 4; ++t) {
            f32x4 acc = {0.f, 0.f, 0.f, 0.f};
            acc = __builtin_amdgcn_mfma_f32_16x16x32_bf16(A2[0], B2[0][t], acc, 0, 0, 0);
            acc = __builtin_amdgcn_mfma_f32_16x16x32_bf16(A2[1], B2[1][t], acc, 0, 0, 0);
            C2[t] = acc;
        }

        float p1v[4] = {0.f, 0.f, 0.f, 0.f}, p2v[4] = {0.f, 0.f, 0.f, 0.f};
        #pragma unroll
        for (int t = 0; t < 4; ++t)
            #pragma unroll
            for (int r = 0; r < 4; ++r) {
                p1v[r] = fmaf(C2[t][r], a1c[t], p1v[r]);
                p2v[r] = fmaf(C2[t][r], a2c[t], p2v[r]);
                const int node = nbase + g * 4 + r;
                if (node < n_nodes)
                    zb[(size_t)node * OUTD + t * 16 + c] = (ushort)f2bf(C2[t][r]);
            }

        #pragma unroll
        for (int r = 0; r < 4; ++r) {
            p1v[r] += __shfl_xor(p1v[r], 1, 64);
            p1v[r] += __shfl_xor(p1v[r], 2, 64);
            p1v[r] += __shfl_xor(p1v[r], 4, 64);
            p1v[r] += __shfl_xor(p1v[r], 8, 64);
            p2v[r] += __shfl_xor(p2v[r], 1, 64);
            p2v[r] += __shfl_xor(p2v[r], 2, 64);
            p2v[r] += __shfl_xor(p2v[r], 4, 64);
            p2v[r] += __shfl_xor(p2v[r], 8, 64);
        }
        const float v1 = (c == 0) ? p1v[0] : (c == 1) ? p1v[1] : (c == 2) ? p1v[2] : p1v[3];
        const float v2 = (c == 0) ? p2v[0] : (c == 1) ? p2v[1] : (c == 2) ? p2v[2] : p2v[3];
        const int snode = nbase + g * 4 + c;
        if (c < 4 && snode < n_nodes) { s1[snode] = v1; s2[snode] = v2; }
        __syncthreads();
    }
}

// ---------------------------------------------------------------------------
// CSR build v4: DETERMINISTIC two-pass radix-partition. No run-time ordering
// resource anywhere (R5: LDS-atomic serialization; R6: one-cache-line global
// atomic serialization, 572us at 0.95% VALUBusy).
//   Pass A  k_bcount: fixed wave<->tile map; ballot-popc per partition ->
//           wcnt[p*NW + w]   (no atomics)
//   k_wtot/k_off8g/k_wscan: partition totals, exclusive off8, per-wave bases
//           (wcnt becomes base[p][w] in place)
//   Pass B  k_bwrite: identical wave<->tile map; 8 running bases in regs;
//           ballot-prefix slot per lane. (no atomics)
// Pack: (dst_local<<17)|src needs n_nodes<=131072, part_sz<=16384.
// ---------------------------------------------------------------------------
__global__ __launch_bounds__(256) void k_bcount(
    const int* __restrict__ dst, int* __restrict__ wcnt, int n_edges,
    int part_sz)
{
    const int lane = threadIdx.x & 63;
    const int gw = (blockIdx.x * 256 + threadIdx.x) >> 6;
    const int nw = (gridDim.x * 256) >> 6;

    int cnt[NPART];
    #pragma unroll
    for (int p = 0; p < NPART; ++p) cnt[p] = 0;

    const int tiles = (n_edges + 255) >> 8;
    for (int t = gw; t < tiles; t += nw) {
        const int base = (t << 8) + (lane << 2);
        int p0 = -1, p1 = -1, p2 = -1, p3 = -1;
        if (base + 3 < n_edges) {
            const int4 d4 = *(const int4*)(dst + base);
            p0 = d4.x / part_sz; p1 = d4.y / part_sz;
            p2 = d4.z / part_sz; p3 = d4.w / part_sz;
        } else {
            if (base + 0 < n_edges) p0 = dst[base + 0] / part_sz;
            if (base + 1 < n_edges) p1 = dst[base + 1] / part_sz;
            if (base + 2 < n_edges) p2 = dst[base + 2] / part_sz;
            if (base + 3 < n_edges) p3 = dst[base + 3] / part_sz;
        }
        #pragma unroll
        for (int pp = 0; pp < NPART; ++pp) {
            cnt[pp] += __popcll(__ballot(p0 == pp)) + __popcll(__ballot(p1 == pp))
                     + __popcll(__ballot(p2 == pp)) + __popcll(__ballot(p3 == pp));
        }
    }
    if (lane == 0) {
        #pragma unroll
        for (int pp = 0; pp < NPART; ++pp) wcnt[pp * nw + gw] = cnt[pp];
    }
}

__global__ __launch_bounds__(256) void k_wtot(
    const int* __restrict__ wcnt, int* __restrict__ tot8, int nw)
{
    __shared__ int sb[256];
    const int p = blockIdx.x, tid = threadIdx.x;
    int s = 0;
    for (int i = tid; i < nw; i += 256) s += wcnt[p * nw + i];
    sb[tid] = s;
    __syncthreads();
    #pragma unroll
    for (int off = 128; off; off >>= 1) {
        if (tid < off) sb[tid] += sb[tid + off];
        __syncthreads();
    }
    if (tid == 0) tot8[p] = sb[0];
}

__global__ void k_off8g(const int* __restrict__ tot8, int* __restrict__ off8)
{
    if (threadIdx.x == 0) {
        int a = 0;
        for (int p = 0; p < NPART; ++p) { off8[p] = a; a += tot8[p]; }
        off8[NPART] = a;
    }
}

__global__ __launch_bounds__(256) void k_wscan(
    int* __restrict__ wcnt, const int* __restrict__ off8, int nw)
{
    __shared__ int buf[256];
    const int p = blockIdx.x, tid = threadIdx.x;
    int running = off8[p];
    for (int c0 = 0; c0 < nw; c0 += 256) {
        const int i = c0 + tid;
        const int v = (i < nw) ? wcnt[p * nw + i] : 0;
        buf[tid] = v;
        __syncthreads();
        #pragma unroll
        for (int off = 1; off < 256; off <<= 1) {
            int t = (tid >= off) ? buf[tid - off] : 0;
            __syncthreads();
            buf[tid] += t;
            __syncthreads();
        }
        if (i < nw) wcnt[p * nw + i] = running + buf[tid] - v;
        running += buf[255];
        __syncthreads();
    }
}

__global__ __launch_bounds__(256) void k_bwrite(
    const int* __restrict__ src, const int* __restrict__ dst,
    const int* __restrict__ wbase, unsigned* __restrict__ bkt,
    int n_edges, int part_sz)
{
    const int lane = threadIdx.x & 63;
    const int gw = (blockIdx.x * 256 + threadIdx.x) >> 6;
    const int nw = (gridDim.x * 256) >> 6;
    const unsigned long long below = (lane == 63) ? 0x7FFFFFFFFFFFFFFFull
                                                  : ((1ull << lane) - 1ull);

    int base8[NPART];
    #pragma unroll
    for (int pp = 0; pp < NPART; ++pp) base8[pp] = wbase[pp * nw + gw];

    const int tiles = (n_edges + 255) >> 8;
    for (int t = gw; t < tiles; t += nw) {
        const int base = (t << 8) + (lane << 2);
        int p[4]; unsigned pk[4];
        if (base + 3 < n_edges) {
            const int4 d4 = *(const int4*)(dst + base);
            const int4 s4 = *(const int4*)(src + base);
            p[0] = d4.x / part_sz; pk[0] = ((unsigned)(d4.x - p[0] * part_sz) << 17) | (unsigned)s4.x;
            p[1] = d4.y / part_sz; pk[1] = ((unsigned)(d4.y - p[1] * part_sz) << 17) | (unsigned)s4.y;
            p[2] = d4.z / part_sz; pk[2] = ((unsigned)(d4.z - p[2] * part_sz) << 17) | (unsigned)s4.z;
            p[3] = d4.w / part_sz; pk[3] = ((unsigned)(d4.w - p[3] * part_sz) << 17) | (unsigned)s4.w;
        } else {
            #pragma unroll
            for (int j = 0; j < 4; ++j) {
                if (base + j < n_edges) {
                    const int d = dst[base + j];
                    p[j] = d / part_sz;
                    pk[j] = ((unsigned)(d - p[j] * part_sz) << 17) | (unsigned)src[base + j];
                } else p[j] = -1;
            }
        }
        #pragma unroll
        for (int pp = 0; pp < NPART; ++pp) {
            const unsigned long long m0 = __ballot(p[0] == pp);
            const unsigned long long m1 = __ballot(p[1] == pp);
            const unsigned long long m2 = __ballot(p[2] == pp);
            const unsigned long long m3 = __ballot(p[3] == pp);
            const int k0 = __popcll(m0), k1 = __popcll(m1);
            const int k2 = __popcll(m2), k3 = __popcll(m3);
            const int go = base8[pp];
            if ((m0 >> lane) & 1) bkt[go + __popcll(m0 & below)] = pk[0];
            if ((m1 >> lane) & 1) bkt[go + k0 + __popcll(m1 & below)] = pk[1];
            if ((m2 >> lane) & 1) bkt[go + k0 + k1 + __popcll(m2 & below)] = pk[2];
            if ((m3 >> lane) & 1) bkt[go + k0 + k1 + k2 + __popcll(m3 & below)] = pk[3];
            base8[pp] = go + k0 + k1 + k2 + k3;
        }
    }
}

__global__ __launch_bounds__(256) void k_hist_b(
    const unsigned* __restrict__ bkt, const int* __restrict__ tot8,
    const int* __restrict__ off8, int* __restrict__ deg, int part_sz)
{
    const int p = blockIdx.x & (NPART - 1);
    const int n = tot8[p];
    const unsigned* b = bkt + off8[p];
    const int lo = p * part_sz;
    const int stride = (gridDim.x >> 3) * 256;
    for (int i = (blockIdx.x >> 3) * 256 + threadIdx.x; i < n; i += stride)
        atomicAdd(&deg[lo + (int)(b[i] >> 17)], 1);
}

__global__ __launch_bounds__(256) void k_scatter_b(
    const unsigned* __restrict__ bkt, const int* __restrict__ tot8,
    const int* __restrict__ off8, int* __restrict__ cursor,
    int* __restrict__ csr, int part_sz)
{
    const int p = blockIdx.x & (NPART - 1);
    const int n = tot8[p];
    const unsigned* b = bkt + off8[p];
    const int lo = p * part_sz;
    const int stride = (gridDim.x >> 3) * 256;
    for (int i = (blockIdx.x >> 3) * 256 + threadIdx.x; i < n; i += stride) {
        const unsigned v = b[i];
        const int d = lo + (int)(v >> 17);
        const int pos = atomicAdd(&cursor[d], 1);
        csr[pos] = (int)(v & 0x1FFFFu);
    }
}

__global__ __launch_bounds__(1024) void k_scan_block(
    const int* __restrict__ deg, int* __restrict__ rs,
    int* __restrict__ bsum, int n)
{
    __shared__ int buf[1024];
    const int tid = threadIdx.x;
    const int gid = blockIdx.x * 1024 + tid;
    const int v = (gid < n) ? deg[gid] : 0;
    buf[tid] = v;
    __syncthreads();
    #pragma unroll
    for (int off = 1; off < 1024; off <<= 1) {
        int t = (tid >= off) ? buf[tid - off] : 0;
        __syncthreads();
        buf[tid] += t;
        __syncthreads();
    }
    if (gid < n) rs[gid] = buf[tid] - v;
    if (tid == 1023) bsum[blockIdx.x] = buf[1023];
}

__global__ __launch_bounds__(128) void k_scan_bsum(int* __restrict__ bsum, int nb)
{
    __shared__ int buf[128];
    const int tid = threadIdx.x;
    const int v = (tid < nb) ? bsum[tid] : 0;
    buf[tid] = v;
    __syncthreads();
    #pragma unroll
    for (int off = 1; off < 128; off <<= 1) {
        int t = (tid >= off) ? buf[tid - off] : 0;
        __syncthreads();
        buf[tid] += t;
        __syncthreads();
    }
    if (tid < nb) bsum[tid] = buf[tid] - v;
}

__global__ __launch_bounds__(1024) void k_add_off(
    int* __restrict__ rs, int* __restrict__ cursor,
    const int* __restrict__ bsum, int n)
{
    const int gid = blockIdx.x * 1024 + threadIdx.x;
    if (gid < n) {
        const int v = rs[gid] + bsum[blockIdx.x];
        rs[gid] = v;
        cursor[gid] = v;
    }
}

// ---------------------------------------------------------------------------
// K_agg: wave per dst node, unroll-4 over edges (4 gathers in flight).
// ---------------------------------------------------------------------------
__global__ __launch_bounds__(256) void gat_agg(
    const int* __restrict__ rs, const int* __restrict__ deg,
    const int* __restrict__ csr,
    const float* __restrict__ s1, const float* __restrict__ s2,
    const ushort* __restrict__ zb, float* __restrict__ h, int n_nodes)
{
    const int wv = threadIdx.x >> 6, lane = threadIdx.x & 63;
    const int node = blockIdx.x * 4 + wv;
    if (node >= n_nodes) return;

    const int base = rs[node];
    const int cnt = deg[node];
    const float s2d = s2[node];

    float acc = 0.f, den = 0.f;
    for (int c0 = 0; c0 < cnt; c0 += 64) {
        const int m = min(64, cnt - c0);
        int sidx = 0;
        float exv = 0.f;
        if (lane < m) {
            sidx = csr[base + c0 + lane];
            float e = s1[sidx] + s2d;
            e = e > 0.f ? e : 0.01f * e;
            exv = __expf(e);
        }
        float dsum = exv;
        WREDUCE(dsum);
        den += dsum;

        const int mr = (m + 3) & ~3;
        for (int j = 0; j < mr; j += 4) {
            const int   i0 = __shfl(sidx, j,     64);
            const int   i1 = __shfl(sidx, j + 1, 64);
            const int   i2 = __shfl(sidx, j + 2, 64);
            const int   i3 = __shfl(sidx, j + 3, 64);
            const float e0 = __shfl(exv,  j,     64);
            const float e1 = __shfl(exv,  j + 1, 64);
            const float e2 = __shfl(exv,  j + 2, 64);
            const float e3 = __shfl(exv,  j + 3, 64);
            const float v0 = bf2f(zb[(size_t)i0 * OUTD + lane]);
            const float v1 = bf2f(zb[(size_t)i1 * OUTD + lane]);
            const float v2 = bf2f(zb[(size_t)i2 * OUTD + lane]);
            const float v3 = bf2f(zb[(size_t)i3 * OUTD + lane]);
            acc = fmaf(e0, v0, acc);
            acc = fmaf(e1, v1, acc);
            acc = fmaf(e2, v2, acc);
            acc = fmaf(e3, v3, acc);
        }
    }
    h[(size_t)node * OUTD + lane] = acc / fmaxf(den, 1e-9f);
}

extern "C" void kernel_launch(void* const* d_in, const int* in_sizes, int n_in,
                              void* d_out, int out_size, void* d_ws, size_t ws_size,
                              hipStream_t stream)
{
    const float* x    = (const float*)d_in[0];
    const float* w_in = (const float*)d_in[1];
    const float* b_in = (const float*)d_in[2];
    const float* w    = (const float*)d_in[3];
    const float* a    = (const float*)d_in[4];
    const int*   src  = (const int*)d_in[5];
    const int*   dst  = (const int*)d_in[6];
    const int n_nodes = in_sizes[0] / IN_DIM;
    const int n_edges = in_sizes[5];

    float* h = (float*)d_out;

    const int NW = BKT_BLOCKS * 4;   // waves in bucket kernels

    // workspace layout (~29 MB)
    ushort*   zb     = (ushort*)d_ws;                        // n_nodes*64 bf16
    float*    s1     = (float*)(zb + (size_t)n_nodes * OUTD);
    float*    s2     = s1 + n_nodes;
    int*      deg    = (int*)(s2 + n_nodes);                 // n_nodes
    int*      tot8   = deg + n_nodes;                        // 8
    int*      off8   = tot8 + NPART;                         // 9 (+pad to 64 total)
    int*      rs     = deg + n_nodes + 64;                   // n_nodes
    int*      cursor = rs + n_nodes;                         // n_nodes
    int*      bsum   = cursor + n_nodes;                     // 128
    int*      csr    = bsum + 128;                           // n_edges
    unsigned* bkt    = (unsigned*)(csr + n_edges);           // n_edges
    int*      wcnt   = (int*)(bkt + n_edges);                // 8*NW

    const int nb = (n_nodes + 1023) / 1024;
    const int ntiles = (n_nodes + 63) / 64;
    const int part_sz = (n_nodes + NPART - 1) / NPART;

    hipMemsetAsync(deg, 0, (size_t)(n_nodes + 64) * sizeof(int), stream);

    k_bcount<<<BKT_BLOCKS, 256, 0, stream>>>(dst, wcnt, n_edges, part_sz);
    k_wtot<<<NPART, 256, 0, stream>>>(wcnt, tot8, NW);
    k_off8g<<<1, 64, 0, stream>>>(tot8, off8);
    k_wscan<<<NPART, 256, 0, stream>>>(wcnt, off8, NW);
    k_bwrite<<<BKT_BLOCKS, 256, 0, stream>>>(src, dst, wcnt, bkt, n_edges, part_sz);
    k_hist_b<<<2048, 256, 0, stream>>>(bkt, tot8, off8, deg, part_sz);
    k_scan_block<<<nb, 1024, 0, stream>>>(deg, rs, bsum, n_nodes);
    k_scan_bsum<<<1, 128, 0, stream>>>(bsum, nb);
    k_add_off<<<nb, 1024, 0, stream>>>(rs, cursor, bsum, n_nodes);
    k_scatter_b<<<2048, 256, 0, stream>>>(bkt, tot8, off8, cursor, csr, part_sz);

    gat_node_proj_mfma<<<523, 256, 0, stream>>>(x, w_in, b_in, w, a,
                                                zb, s1, s2, n_nodes, ntiles);

    gat_agg<<<(n_nodes + 3) / 4, 256, 0, stream>>>(rs, deg, csr, s1, s2, zb, h, n_nodes);
}